// Round 1
// baseline (158.242 us; speedup 1.0000x reference)
//
#include <hip/hip_runtime.h>
#include <cstdint>
#include <cstddef>

namespace {
constexpr int kN    = 65536;     // nodes
constexpr int kF    = 256;       // feats
constexpr int kC    = 64;        // pools per graph
constexpr int kNPG  = 1024;      // nodes per graph
constexpr int kB    = 64;        // graphs
constexpr int kE    = 2097152;   // edges
constexpr int kK    = kB * kC;   // 4096 global clusters

// d_out offsets (in floats)
constexpr size_t OFF_OUT  = 0;                           // [4096,256]
constexpr size_t OFF_EIDX = (size_t)kK * kF;             // 1048576  [2,262144]
constexpr size_t OFF_ADJ  = OFF_EIDX + 2ull*kB*kC*kC;    // 1572864  [262144]
constexpr size_t OFF_LL   = OFF_ADJ + (size_t)kB*kC*kC;  // 1835008
constexpr size_t OFF_Z    = OFF_LL + 1;                  // 1835009
constexpr size_t OFF_BOUT = OFF_Z + 1;                   // 1835010  [4096]
constexpr size_t OFF_BPTR = OFF_BOUT + kK;               // 1839106  [65]

// ws offsets (bytes)
constexpr size_t WS_C    = 0;        // int[65536]
constexpr size_t WS_V    = 262144;   // float[65536]
constexpr size_t WS_VS2  = 524288;   // float[4096]
constexpr size_t WS_A2   = 540672;   // float[256]
constexpr size_t WS_PADJ = 544768;   // float[256*4096] = 4 MiB
} // namespace

// ---------------------------------------------------------------- constants
__global__ __launch_bounds__(256) void k_const(float* __restrict__ out)
{
    const int i = blockIdx.x * 256 + threadIdx.x;
    constexpr int E2 = 2 * kB * kC * kC;      // 524288
    if (i < E2) {
        const int half = i >= kB*kC*kC;
        const int idx  = half ? i - kB*kC*kC : i;
        const int bb = idx >> 12, rem = idx & 4095;
        const int val = half ? bb*kC + (rem & 63) : bb*kC + (rem >> 6);
        out[OFF_EIDX + i] = (float)val;
    } else if (i < E2 + kK) {
        const int j = i - E2;
        out[OFF_BOUT + j] = (float)(j >> 6);
    } else if (i < E2 + kK + kB + 1) {
        const int j = i - (E2 + kK);
        out[OFF_BPTR + j] = (float)(j * kC);
    }
}

// ------------------------------------------------- K1: logits -> c, v
// GEMM M=65536 N=64 K=256, block = 256 thr, BM=128 nodes, reg tile 4x8.
__global__ __launch_bounds__(256) void k_logits(
    const float* __restrict__ x, const float* __restrict__ Wm,
    const float* __restrict__ bv, int* __restrict__ carr,
    float* __restrict__ varr)
{
    constexpr int BM = 128, KCc = 32, BMP = 132;  // pad -> conflict-free b128
    __shared__ float xs[KCc][BMP];   // transposed tile  [k][node]
    __shared__ float wsd[KCc][kC];
    const int tid = threadIdx.x;
    const int tx  = tid & 7;    // col group: cols tx*8 .. tx*8+7
    const int ty  = tid >> 3;   // row group: rows ty*4 .. ty*4+3
    const int nbase = blockIdx.x * BM;

    float acc[4][8];
#pragma unroll
    for (int j = 0; j < 8; ++j) {
        const float bb = bv[tx*8 + j];
#pragma unroll
        for (int i = 0; i < 4; ++i) acc[i][j] = bb;
    }

    for (int kc = 0; kc < kF; kc += KCc) {
        __syncthreads();
#pragma unroll
        for (int r = 0; r < 4; ++r) {
            const int idx  = tid + 256*r;     // 0..1023 float4 slots
            const int node = idx >> 3;
            const int k4   = (idx & 7) << 2;
            const float4 g = *reinterpret_cast<const float4*>(
                x + (size_t)(nbase + node)*kF + kc + k4);
            xs[k4+0][node] = g.x; xs[k4+1][node] = g.y;
            xs[k4+2][node] = g.z; xs[k4+3][node] = g.w;
        }
#pragma unroll
        for (int r = 0; r < 8; ++r) {
            const int idx = tid + 256*r;      // 0..2047
            wsd[idx >> 6][idx & 63] =
                Wm[(size_t)(kc + (idx >> 6))*kC + (idx & 63)];
        }
        __syncthreads();
#pragma unroll
        for (int kk = 0; kk < KCc; ++kk) {
            const float4 xa = *reinterpret_cast<const float4*>(&xs[kk][ty*4]);
            const float4 wa = *reinterpret_cast<const float4*>(&wsd[kk][tx*8]);
            const float4 wb = *reinterpret_cast<const float4*>(&wsd[kk][tx*8+4]);
            const float xv[4] = {xa.x, xa.y, xa.z, xa.w};
            const float wv[8] = {wa.x, wa.y, wa.z, wa.w,
                                 wb.x, wb.y, wb.z, wb.w};
#pragma unroll
            for (int i = 0; i < 4; ++i)
#pragma unroll
                for (int j = 0; j < 8; ++j)
                    acc[i][j] = fmaf(xv[i], wv[j], acc[i][j]);
        }
    }

    // per-node softmax-argmax over 64 cols spread across 8 lanes x 8 regs
#pragma unroll
    for (int i = 0; i < 4; ++i) {
        float m = acc[i][0];
        int   ci = tx*8;
#pragma unroll
        for (int j = 1; j < 8; ++j)
            if (acc[i][j] > m) { m = acc[i][j]; ci = tx*8 + j; }
#pragma unroll
        for (int off = 1; off < 8; off <<= 1) {
            const float om = __shfl_xor(m, off);
            const int   oc = __shfl_xor(ci, off);
            if (om > m || (om == m && oc < ci)) { m = om; ci = oc; }
        }
        float s = 0.f;
#pragma unroll
        for (int j = 0; j < 8; ++j) s += expf(acc[i][j] - m);
#pragma unroll
        for (int off = 1; off < 8; off <<= 1) s += __shfl_xor(s, off);
        if (tx == 0) {
            const float p = 1.0f / s;
            const int n = nbase + ty*4 + i;
            carr[n] = ci;
            varr[n] = (1.0f - p) + p;   // straight-through forward value
        }
    }
}

// ------------------------------------- K2: out = S^T x  (+ vs2), atomic-free
// block = (graph, feat-quarter); exclusive ownership of its 64x64 out slab.
__global__ __launch_bounds__(256) void k_pool_x(
    const float* __restrict__ x, const int* __restrict__ carr,
    const float* __restrict__ varr, float* __restrict__ out,
    float* __restrict__ vs2)
{
    __shared__ float acc[kC][65];
    __shared__ float acc2[kC];
    const int tid = threadIdx.x;
    const int g   = blockIdx.x >> 2;
    const int fq  = blockIdx.x & 3;
    for (int i = tid; i < kC*65; i += 256) (&acc[0][0])[i] = 0.f;
    if (tid < kC) acc2[tid] = 0.f;
    __syncthreads();

    const int q   = tid & 15;    // feat lane (16 per node)
    const int sub = tid >> 4;    // node sub-index (0..15)
    const int fbase = fq*64 + q*4;
    for (int it = 0; it < 64; it += 4) {
        float4 xv[4]; int cn[4]; float vn[4];
#pragma unroll
        for (int u = 0; u < 4; ++u) {
            const int n = g*kNPG + (it+u)*16 + sub;
            xv[u] = *reinterpret_cast<const float4*>(x + (size_t)n*kF + fbase);
            cn[u] = carr[n];
            vn[u] = varr[n];
        }
#pragma unroll
        for (int u = 0; u < 4; ++u) {
            float* row = acc[cn[u]];
            atomicAdd(&row[q*4+0], vn[u]*xv[u].x);
            atomicAdd(&row[q*4+1], vn[u]*xv[u].y);
            atomicAdd(&row[q*4+2], vn[u]*xv[u].z);
            atomicAdd(&row[q*4+3], vn[u]*xv[u].w);
            if (fq == 0 && q == 0) atomicAdd(&acc2[cn[u]], vn[u]*vn[u]);
        }
    }
    __syncthreads();
#pragma unroll
    for (int r = 0; r < 16; ++r) {
        const int lin = r*256 + tid;
        const int c = lin >> 6, fl = lin & 63;
        out[OFF_OUT + (size_t)(g*kC + c)*kF + fq*64 + fl] = acc[c][fl];
    }
    if (fq == 0 && tid < kC) vs2[g*kC + tid] = acc2[tid];
}

// ------------------------------------- K4: adjacency partials (+ a2 partial)
__global__ __launch_bounds__(256) void k_adj(
    const int* __restrict__ ei, const float* __restrict__ ew,
    const int* __restrict__ carr, const float* __restrict__ varr,
    float* __restrict__ padj, float* __restrict__ a2p)
{
    __shared__ float adj[kC*kC];
    __shared__ float wred[4];
    const int tid = threadIdx.x;
    const int bid = blockIdx.x;             // 256 blocks = 64 graphs x 4
    for (int i = tid; i < kC*kC; i += 256) adj[i] = 0.f;
    __syncthreads();
    const int e0 = bid * 8192;
    float a2l = 0.f;
    for (int it = 0; it < 32; it += 4) {
        int sn[4], dn[4]; float w[4];
#pragma unroll
        for (int u = 0; u < 4; ++u) {
            const int e = e0 + (it+u)*256 + tid;
            sn[u] = ei[e]; dn[u] = ei[kE + e]; w[u] = ew[e];
        }
        int ci[4], cj[4]; float vv[4];
#pragma unroll
        for (int u = 0; u < 4; ++u) {
            ci[u] = carr[sn[u]]; cj[u] = carr[dn[u]];
            vv[u] = varr[sn[u]] * varr[dn[u]];
        }
#pragma unroll
        for (int u = 0; u < 4; ++u) {
            atomicAdd(&adj[ci[u]*kC + cj[u]], w[u]*vv[u]);
            a2l += w[u]*w[u];
        }
    }
    __syncthreads();
#pragma unroll
    for (int r = 0; r < 16; ++r) {
        const int lin = r*256 + tid;
        padj[(size_t)bid*4096 + lin] = adj[lin];
    }
#pragma unroll
    for (int off = 32; off > 0; off >>= 1) a2l += __shfl_down(a2l, off);
    if ((tid & 63) == 0) wred[tid >> 6] = a2l;
    __syncthreads();
    if (tid == 0) a2p[bid] = wred[0] + wred[1] + wred[2] + wred[3];
}

// ------------------------------------- K5: merge adjacency partials
__global__ __launch_bounds__(256) void k_adj_merge(
    const float* __restrict__ padj, float* __restrict__ out)
{
    const int id = blockIdx.x*256 + threadIdx.x;   // < 262144
    const int g = id >> 12, idx = id & 4095;
    float s = 0.f;
#pragma unroll
    for (int sp = 0; sp < 4; ++sp) s += padj[(size_t)(g*4 + sp)*4096 + idx];
    out[OFF_ADJ + id] = s;
}

// ------------------------------------- K6: link_loss scalar
__global__ __launch_bounds__(256) void k_final(
    const float* __restrict__ vs2, const float* __restrict__ a2p,
    float* __restrict__ out)
{
    const int tid = threadIdx.x;
    float p2l = 0.f, apl = 0.f;
#pragma unroll
    for (int r = 0; r < 16; ++r) {
        const int k = r*256 + tid;
        const float t = vs2[k];
        p2l += t*t;
        const int g = k >> 6, cc = k & 63;
        apl += out[OFF_ADJ + (size_t)g*4096 + cc*65];   // diagonal entries
    }
    float a2l = a2p[tid];
#pragma unroll
    for (int off = 32; off > 0; off >>= 1) {
        p2l += __shfl_down(p2l, off);
        apl += __shfl_down(apl, off);
        a2l += __shfl_down(a2l, off);
    }
    __shared__ float red[3][4];
    if ((tid & 63) == 0) {
        red[0][tid>>6] = p2l; red[1][tid>>6] = apl; red[2][tid>>6] = a2l;
    }
    __syncthreads();
    if (tid == 0) {
        const float p2 = red[0][0]+red[0][1]+red[0][2]+red[0][3];
        const float ap = red[1][0]+red[1][1]+red[1][2]+red[1][3];
        const float a2 = red[2][0]+red[2][1]+red[2][2]+red[2][3];
        const float val = a2 - 2.0f*ap + p2;
        out[OFF_LL] = sqrtf(fmaxf(val, 0.f)) / (float)kE;
        out[OFF_Z]  = 0.0f;
    }
}

// ----------------------------------------------------------------- launch
extern "C" void kernel_launch(void* const* d_in, const int* in_sizes, int n_in,
                              void* d_out, int out_size, void* d_ws, size_t ws_size,
                              hipStream_t stream)
{
    const float* x  = (const float*)d_in[0];
    const int*   ei = (const int*)d_in[1];
    const float* ew = (const float*)d_in[2];
    // d_in[3] = batch, d_in[4] = batch_ptr: implied by block structure
    const float* Wm = (const float*)d_in[5];
    const float* bv = (const float*)d_in[6];
    float* out = (float*)d_out;
    char*  ws  = (char*)d_ws;
    int*   carr = (int*)(ws + WS_C);
    float* varr = (float*)(ws + WS_V);
    float* vs2  = (float*)(ws + WS_VS2);
    float* a2p  = (float*)(ws + WS_A2);
    float* padj = (float*)(ws + WS_PADJ);

    k_const    <<<2065, 256, 0, stream>>>(out);
    k_logits   <<<512,  256, 0, stream>>>(x, Wm, bv, carr, varr);
    k_pool_x   <<<256,  256, 0, stream>>>(x, carr, varr, out, vs2);
    k_adj      <<<256,  256, 0, stream>>>(ei, ew, carr, varr, padj, a2p);
    k_adj_merge<<<1024, 256, 0, stream>>>(padj, out);
    k_final    <<<1,    256, 0, stream>>>(vs2, a2p, out);
}